// Round 1
// baseline (4701.558 us; speedup 1.0000x reference)
//
#include <hip/hip_runtime.h>

#define N4K 4096
#define DFEAT 256
constexpr float P_UNIF = 1.0f / 4096.0f;

typedef __attribute__((ext_vector_type(8))) short bf16x8;
typedef __attribute__((ext_vector_type(4))) float f32x4;

__device__ __forceinline__ float bfl(unsigned u) { return __uint_as_float(u << 16); }
__device__ __forceinline__ float bfh(unsigned u) { return __uint_as_float(u & 0xffff0000u); }
__device__ __forceinline__ unsigned short f2bf(float f) {
  unsigned u = __float_as_uint(f);
  u += 0x7fffu + ((u >> 16) & 1u);   // RNE
  return (unsigned short)(u >> 16);
}
__device__ __forceinline__ void load_lds16(const void* g, void* l) {
  __builtin_amdgcn_global_load_lds(
      (const __attribute__((address_space(1))) void*)g,
      (__attribute__((address_space(3))) void*)l, 16, 0, 0);
}

// ---------------- row-normalize + cast to bf16 -------------------------------
__global__ void k_normalize(const float* __restrict__ in, unsigned short* __restrict__ out) {
  const int wv = threadIdx.x >> 6, lane = threadIdx.x & 63;
  const int row = blockIdx.x * 4 + wv;
  const float4 v = ((const float4*)(in + (size_t)row * DFEAT))[lane];
  float ss = v.x * v.x + v.y * v.y + v.z * v.z + v.w * v.w;
#pragma unroll
  for (int off = 32; off; off >>= 1) ss += __shfl_xor(ss, off);
  const float inv = rsqrtf(ss);
  unsigned a = (unsigned)f2bf(v.x * inv) | ((unsigned)f2bf(v.y * inv) << 16);
  unsigned b = (unsigned)f2bf(v.z * inv) | ((unsigned)f2bf(v.w * inv) << 16);
  ((uint2*)(out + (size_t)row * DFEAT))[lane] = make_uint2(a, b);
}

// ---------------- m97-pattern bf16 GEMM: C = A @ B^T -------------------------
// A: [M x K] row-major bf16, B: [N x K] row-major bf16 (i.e. B^T input), ld = K stride.
// mode 0: out = bf16(acc)          (Aprime = H2hat @ T^T)
// mode 1: out = bf16(-acc)         (S = -X@X^T = cos-dist minus 1)
// mode 2: out = bf16(exp((acc - ct[col]) * 20))   (Gibbs kernel, eps = 0.05)
__global__ __launch_bounds__(256) void k_gemm_bt(
    const unsigned short* __restrict__ A, const unsigned short* __restrict__ B,
    int ld, int K, unsigned short* __restrict__ out,
    int mode, const float* __restrict__ ct)
{
  __shared__ unsigned short Als[128 * 32];
  __shared__ unsigned short Bls[128 * 32];
  const int tid = threadIdx.x;
  const int w = tid >> 6, lane = tid & 63;
  const int wr = w >> 1, wc = w & 1;                 // 2x2 waves, 64x64 each
  const int mbase = blockIdx.y * 128, nbase = blockIdx.x * 128;

  const f32x4 fz = {0.f, 0.f, 0.f, 0.f};
  f32x4 acc[4][4];
#pragma unroll
  for (int m = 0; m < 4; m++)
#pragma unroll
    for (int n = 0; n < 4; n++) acc[m][n] = fz;

  // staging: wave w covers tile rows [w*32, w*32+32) via 2 chunks of 16 rows (1KB each)
  const int sRow = lane >> 2;            // 0..15
  const int sCol = (lane & 3) * 8;       // 0,8,16,24
  const unsigned short* gA = A + (size_t)(mbase + w * 32 + sRow) * ld + sCol;
  const unsigned short* gB = B + (size_t)(nbase + w * 32 + sRow) * ld + sCol;
  unsigned short* lA0 = &Als[(w * 2 + 0) * 512];
  unsigned short* lA1 = &Als[(w * 2 + 1) * 512];
  unsigned short* lB0 = &Bls[(w * 2 + 0) * 512];
  unsigned short* lB1 = &Bls[(w * 2 + 1) * 512];

  const int rA = lane & 15, kg = (lane >> 4) * 8;

  for (int k0 = 0; k0 < K; k0 += 32) {
    __syncthreads();
    load_lds16(gA + k0, lA0);
    load_lds16(gA + (size_t)16 * ld + k0, lA1);
    load_lds16(gB + k0, lB0);
    load_lds16(gB + (size_t)16 * ld + k0, lB1);
    __syncthreads();   // compiler drains vmcnt before barrier
    bf16x8 a[4], b[4];
#pragma unroll
    for (int m = 0; m < 4; m++)
      a[m] = *(const bf16x8*)&Als[(wr * 64 + m * 16 + rA) * 32 + kg];
#pragma unroll
    for (int n = 0; n < 4; n++)
      b[n] = *(const bf16x8*)&Bls[(wc * 64 + n * 16 + rA) * 32 + kg];
#pragma unroll
    for (int m = 0; m < 4; m++)
#pragma unroll
      for (int n = 0; n < 4; n++)
        acc[m][n] = __builtin_amdgcn_mfma_f32_16x16x32_bf16(a[m], b[n], acc[m][n], 0, 0, 0);
  }

  // C/D layout: col = lane&15, row = (lane>>4)*4 + r   [m89-verified]
  const int crow0 = mbase + wr * 64 + (lane >> 4) * 4;
  const int ccol0 = nbase + wc * 64 + (lane & 15);
#pragma unroll
  for (int m = 0; m < 4; m++) {
#pragma unroll
    for (int n = 0; n < 4; n++) {
      const int col = ccol0 + n * 16;
      const float cv = (mode == 2) ? ct[col] : 0.0f;
#pragma unroll
      for (int r = 0; r < 4; r++) {
        const int row = crow0 + m * 16 + r;
        float val = acc[m][n][r];
        if (mode == 1) val = -val;
        else if (mode == 2) val = __expf((val - cv) * 20.0f);
        out[(size_t)row * N4K + col] = f2bf(val);
      }
    }
  }
}

// ---------------- scalar init ------------------------------------------------
__global__ void k_zero1(float* p) { if (threadIdx.x == 0) *p = 0.0f; }

__global__ void k_setones(float* __restrict__ v) {
  v[blockIdx.x * 256 + threadIdx.x] = 1.0f;
}

__global__ void k_fill_bf16(unsigned short* __restrict__ T, unsigned pattern) {
  const size_t c = (size_t)blockIdx.x * 256 + threadIdx.x;
  ((uint4*)T)[c] = make_uint4(pattern, pattern, pattern, pattern);
}

// ---------------- column stats of S (colsum, colsum^2, global max) -----------
__global__ void k_stats(const unsigned short* __restrict__ S, float* __restrict__ psum,
                        float* __restrict__ psq, float* __restrict__ dmax) {
  const int tid = threadIdx.x;
  const int c0 = blockIdx.x * 2048 + tid * 8;
  const int r0 = blockIdx.y * 128;
  float s[8], q2[8];
#pragma unroll
  for (int e = 0; e < 8; e++) { s[e] = 0.f; q2[e] = 0.f; }
  float mx = -2.0f;
  for (int r = 0; r < 128; r++) {
    const uint4 q = *(const uint4*)&S[(size_t)(r0 + r) * N4K + c0];
    const float f0 = bfl(q.x), f1 = bfh(q.x), f2_ = bfl(q.y), f3 = bfh(q.y);
    const float f4 = bfl(q.z), f5 = bfh(q.z), f6 = bfl(q.w), f7 = bfh(q.w);
    s[0] += f0; q2[0] += f0 * f0; mx = fmaxf(mx, f0);
    s[1] += f1; q2[1] += f1 * f1; mx = fmaxf(mx, f1);
    s[2] += f2_; q2[2] += f2_ * f2_; mx = fmaxf(mx, f2_);
    s[3] += f3; q2[3] += f3 * f3; mx = fmaxf(mx, f3);
    s[4] += f4; q2[4] += f4 * f4; mx = fmaxf(mx, f4);
    s[5] += f5; q2[5] += f5 * f5; mx = fmaxf(mx, f5);
    s[6] += f6; q2[6] += f6 * f6; mx = fmaxf(mx, f6);
    s[7] += f7; q2[7] += f7 * f7; mx = fmaxf(mx, f7);
  }
  float* ps = psum + (size_t)blockIdx.y * N4K + c0;
  float* pq = psq + (size_t)blockIdx.y * N4K + c0;
  *(float4*)ps = make_float4(s[0], s[1], s[2], s[3]);
  *(float4*)(ps + 4) = make_float4(s[4], s[5], s[6], s[7]);
  *(float4*)pq = make_float4(q2[0], q2[1], q2[2], q2[3]);
  *(float4*)(pq + 4) = make_float4(q2[4], q2[5], q2[6], q2[7]);

  __shared__ float red[256];
  red[tid] = mx;
  __syncthreads();
  for (int st = 128; st > 0; st >>= 1) {
    if (tid < st) red[tid] = fmaxf(red[tid], red[tid + st]);
    __syncthreads();
  }
  if (tid == 0) atomicMax((int*)dmax, __float_as_int(fmaxf(red[0], 0.0f)));
}

// mode 0: vecout = c1 = (1+cm)/m ; mode 1: vecout = r2 = (1+2cm+cmsq)/m^2
__global__ void k_statsfinal(const float* __restrict__ psum, const float* __restrict__ psq,
                             const float* __restrict__ dmax, float* __restrict__ cm,
                             float* __restrict__ vecout, int mode) {
  const int j = blockIdx.x * 256 + threadIdx.x;
  float s = 0.f, sq = 0.f;
  for (int c = 0; c < 32; c++) {
    s += psum[(size_t)c * N4K + j];
    sq += psq[(size_t)c * N4K + j];
  }
  const float cmean = s * (1.0f / N4K), cmsq = sq * (1.0f / N4K);
  const float m = 1.0f + *dmax;
  cm[j] = cmean;
  if (mode == 0) vecout[j] = (1.0f + cmean) / m;
  else vecout[j] = (1.0f + 2.0f * cmean + cmsq) / (m * m);
}

// out_ij = bf16( (S_ij - cm_j) * sc / (1+max) )   -- column-centered, scaled
__global__ void k_center(const unsigned short* __restrict__ S, const float* __restrict__ cm,
                         const float* __restrict__ dmax, unsigned short* __restrict__ out,
                         float sc) {
  const int c = blockIdx.x * 256 + threadIdx.x;
  const int row = c >> 9;
  const int col0 = (c & 511) * 8;
  const float inv = sc / (1.0f + *dmax);
  const uint4 q = *(const uint4*)&S[(size_t)row * N4K + col0];
  const float4 ca = *(const float4*)&cm[col0];
  const float4 cb = *(const float4*)&cm[col0 + 4];
  unsigned r0 = (unsigned)f2bf((bfl(q.x) - ca.x) * inv) | ((unsigned)f2bf((bfh(q.x) - ca.y) * inv) << 16);
  unsigned r1 = (unsigned)f2bf((bfl(q.y) - ca.z) * inv) | ((unsigned)f2bf((bfh(q.y) - ca.w) * inv) << 16);
  unsigned r2_ = (unsigned)f2bf((bfl(q.z) - cb.x) * inv) | ((unsigned)f2bf((bfh(q.z) - cb.y) * inv) << 16);
  unsigned r3 = (unsigned)f2bf((bfl(q.w) - cb.z) * inv) | ((unsigned)f2bf((bfh(q.w) - cb.w) * inv) << 16);
  *(uint4*)&out[(size_t)row * N4K + col0] = make_uint4(r0, r1, r2_, r3);
}

// ---------------- row matvec: one wave per row -------------------------------
// mode 0: out = sum ; mode 1: out = p/sum ; mode 2: out = r2[row] - sum
__global__ void k_rowmv(const unsigned short* __restrict__ M, const float* __restrict__ x,
                        float* __restrict__ out, int mode, const float* __restrict__ r2) {
  const int wv = threadIdx.x >> 6, lane = threadIdx.x & 63;
  const int row = blockIdx.x * 4 + wv;
  const unsigned short* r = M + (size_t)row * N4K;
  float acc = 0.f;
#pragma unroll
  for (int p = 0; p < 8; p++) {
    const int j0 = p * 512 + lane * 8;
    const uint4 q = *(const uint4*)&r[j0];
    const float4 xa = *(const float4*)&x[j0];
    const float4 xb = *(const float4*)&x[j0 + 4];
    acc += bfl(q.x) * xa.x + bfh(q.x) * xa.y + bfl(q.y) * xa.z + bfh(q.y) * xa.w
         + bfl(q.z) * xb.x + bfh(q.z) * xb.y + bfl(q.w) * xb.z + bfh(q.w) * xb.w;
  }
#pragma unroll
  for (int off = 32; off; off >>= 1) acc += __shfl_xor(acc, off);
  if (lane == 0) {
    if (mode == 0) out[row] = acc;
    else if (mode == 1) out[row] = P_UNIF / acc;
    else out[row] = r2[row] - acc;
  }
}

// ---------------- column matvec (M^T x): partial over 128-row chunks ---------
__global__ void k_colmv(const unsigned short* __restrict__ M, const float* __restrict__ x,
                        float* __restrict__ partials) {
  const int tid = threadIdx.x;
  const int c0 = blockIdx.x * 2048 + tid * 8;
  const int r0 = blockIdx.y * 128;
  float a0 = 0, a1 = 0, a2 = 0, a3 = 0, a4 = 0, a5 = 0, a6 = 0, a7 = 0;
  for (int r = 0; r < 128; r++) {
    const float xv = x[r0 + r];
    const uint4 q = *(const uint4*)&M[(size_t)(r0 + r) * N4K + c0];
    a0 += xv * bfl(q.x); a1 += xv * bfh(q.x);
    a2 += xv * bfl(q.y); a3 += xv * bfh(q.y);
    a4 += xv * bfl(q.z); a5 += xv * bfh(q.z);
    a6 += xv * bfl(q.w); a7 += xv * bfh(q.w);
  }
  float* p = partials + (size_t)blockIdx.y * N4K + c0;
  *(float4*)p = make_float4(a0, a1, a2, a3);
  *(float4*)(p + 4) = make_float4(a4, a5, a6, a7);
}

// mode 0: out = sum ; mode 1: out = q/sum
__global__ void k_colreduce(const float* __restrict__ partials, float* __restrict__ out,
                            int mode) {
  const int j = blockIdx.x * 256 + threadIdx.x;
  float s = 0.f;
  for (int c = 0; c < 32; c++) s += partials[(size_t)c * N4K + j];
  out[j] = (mode == 0) ? s : P_UNIF / s;
}

// ---------------- T = u (.) K (.) v, in place --------------------------------
__global__ void k_scaleT(unsigned short* __restrict__ K, const float* __restrict__ u,
                         const float* __restrict__ v) {
  const int c = blockIdx.x * 256 + threadIdx.x;
  const int row = c >> 9;
  const int col0 = (c & 511) * 8;
  const float ur = u[row];
  unsigned short* p = K + (size_t)row * N4K + col0;
  const uint4 q = *(const uint4*)p;
  const float4 va = *(const float4*)&v[col0];
  const float4 vb = *(const float4*)&v[col0 + 4];
  unsigned r0 = (unsigned)f2bf(ur * bfl(q.x) * va.x) | ((unsigned)f2bf(ur * bfh(q.x) * va.y) << 16);
  unsigned r1 = (unsigned)f2bf(ur * bfl(q.y) * va.z) | ((unsigned)f2bf(ur * bfh(q.y) * va.w) << 16);
  unsigned r2_ = (unsigned)f2bf(ur * bfl(q.z) * vb.x) | ((unsigned)f2bf(ur * bfh(q.z) * vb.y) << 16);
  unsigned r3 = (unsigned)f2bf(ur * bfl(q.w) * vb.z) | ((unsigned)f2bf(ur * bfh(q.w) * vb.w) << 16);
  *(uint4*)p = make_uint4(r0, r1, r2_, r3);
}

// ---------------- loss = -sum log(u_i K_ii v_i + 1e-10) ----------------------
__global__ void k_loss(const unsigned short* __restrict__ K, const float* __restrict__ u,
                       const float* __restrict__ v, float* __restrict__ out) {
  const int tid = threadIdx.x;
  float acc = 0.f;
  for (int i = tid; i < N4K; i += 256) {
    const float d = u[i] * bfl((unsigned)K[(size_t)i * (N4K + 1)]) * v[i];
    acc += logf(d + 1e-10f);
  }
  __shared__ float red[256];
  red[tid] = acc;
  __syncthreads();
  for (int st = 128; st > 0; st >>= 1) {
    if (tid < st) red[tid] += red[tid + st];
    __syncthreads();
  }
  if (tid == 0) out[0] = -red[0];
}

// ============================================================================
extern "C" void kernel_launch(void* const* d_in, const int* in_sizes, int n_in,
                              void* d_out, int out_size, void* d_ws, size_t ws_size,
                              hipStream_t stream) {
  const float* f1 = (const float*)d_in[0];
  const float* f2 = (const float*)d_in[1];
  float* out = (float*)d_out;

  char* w = (char*)d_ws;
  const size_t NN = (size_t)N4K * N4K;
  unsigned short* X1 = (unsigned short*)w;   w += (size_t)N4K * DFEAT * 2;
  unsigned short* X2 = (unsigned short*)w;   w += (size_t)N4K * DFEAT * 2;
  unsigned short* C1h = (unsigned short*)w;  w += NN * 2;   // column-centered C1 (bf16)
  unsigned short* H2h = (unsigned short*)w;  w += NN * 2;   // column-centered 2*C2 (bf16)
  unsigned short* Sbuf = (unsigned short*)w; w += NN * 2;   // S scratch, then Aprime
  unsigned short* T0 = (unsigned short*)w;   w += NN * 2;
  unsigned short* T1 = (unsigned short*)w;   w += NN * 2;
  float* ps1 = (float*)w;  w += (size_t)32 * N4K * 4;
  float* ps2 = (float*)w;  w += (size_t)32 * N4K * 4;
  float* uvec = (float*)w; w += N4K * 4;
  float* vvec = (float*)w; w += N4K * 4;
  float* wvec = (float*)w; w += N4K * 4;
  float* ctv = (float*)w;  w += N4K * 4;
  float* r2v = (float*)w;  w += N4K * 4;
  float* c1v = (float*)w;  w += N4K * 4;
  float* cmv = (float*)w;  w += N4K * 4;
  float* dmax = (float*)w; w += 256;

  const dim3 b256(256);
  const dim3 gGemm(32, 32);
  const dim3 gCol(2, 32);

  k_normalize<<<1024, b256, 0, stream>>>(f1, X1);
  k_normalize<<<1024, b256, 0, stream>>>(f2, X2);

  // ---- cost matrix 1: S = -X1 X1^T ; c1 = colmean(C1) ; C1h = centered ----
  k_gemm_bt<<<gGemm, b256, 0, stream>>>(X1, X1, DFEAT, DFEAT, Sbuf, 1, nullptr);
  k_zero1<<<1, 64, 0, stream>>>(dmax);
  k_stats<<<gCol, b256, 0, stream>>>(Sbuf, ps1, ps2, dmax);
  k_statsfinal<<<16, b256, 0, stream>>>(ps1, ps2, dmax, cmv, c1v, 0);
  k_center<<<8192, b256, 0, stream>>>(Sbuf, cmv, dmax, C1h, 1.0f);

  // ---- cost matrix 2: r2 = rowmean(C2^2) ; H2h = centered 2*C2 ----
  k_gemm_bt<<<gGemm, b256, 0, stream>>>(X2, X2, DFEAT, DFEAT, Sbuf, 1, nullptr);
  k_zero1<<<1, 64, 0, stream>>>(dmax);
  k_stats<<<gCol, b256, 0, stream>>>(Sbuf, ps1, ps2, dmax);
  k_statsfinal<<<16, b256, 0, stream>>>(ps1, ps2, dmax, cmv, r2v, 1);
  k_center<<<8192, b256, 0, stream>>>(Sbuf, cmv, dmax, H2h, 2.0f);

  // ---- T = outer(p,q) = 2^-24 (bf16 0x3380, exact) ----
  k_fill_bf16<<<8192, b256, 0, stream>>>(T0, 0x33803380u);

  unsigned short* Tc = T0;
  unsigned short* Ko = T1;
  for (int it = 0; it < 5; it++) {
    // Aprime = H2h @ Tc^T    (= (Tc @ H2h^T)^T)
    k_gemm_bt<<<gGemm, b256, 0, stream>>>(H2h, Tc, N4K, N4K, Sbuf, 0, nullptr);
    // w = Tc^T c1 ; ct_j = r2_j - (H2h w)_j   (exact fp32 col-constant of tens)
    k_colmv<<<gCol, b256, 0, stream>>>(Tc, c1v, ps1);
    k_colreduce<<<16, b256, 0, stream>>>(ps1, wvec, 0);
    k_rowmv<<<1024, b256, 0, stream>>>(H2h, wvec, ctv, 2, r2v);
    // K = exp((C1h @ Aprime^T - ct_j) / eps)   (row-constants dropped: exact invariance)
    k_gemm_bt<<<gGemm, b256, 0, stream>>>(C1h, Sbuf, N4K, N4K, Ko, 2, ctv);
    // Sinkhorn: 20 x { u = p/(K v) ; v = q/(K^T u) }, v0 = 1
    k_setones<<<16, b256, 0, stream>>>(vvec);
    for (int s = 0; s < 20; s++) {
      k_rowmv<<<1024, b256, 0, stream>>>(Ko, vvec, uvec, 1, nullptr);
      k_colmv<<<gCol, b256, 0, stream>>>(Ko, uvec, ps1);
      k_colreduce<<<16, b256, 0, stream>>>(ps1, vvec, 1);
    }
    if (it < 4) {
      k_scaleT<<<8192, b256, 0, stream>>>(Ko, uvec, vvec);  // K -> T in place
      unsigned short* tmp = Tc; Tc = Ko; Ko = tmp;
    }
  }
  k_loss<<<1, b256, 0, stream>>>(Ko, uvec, vvec, out);
}

// Round 3
// 3822.869 us; speedup vs baseline: 1.2299x; 1.2299x over previous
//
#include <hip/hip_runtime.h>

#define N4K 4096
#define DFEAT 256
constexpr float P_UNIF = 1.0f / 4096.0f;

typedef __attribute__((ext_vector_type(8))) short bf16x8;
typedef __attribute__((ext_vector_type(4))) float f32x4;

__device__ __forceinline__ float bfl(unsigned u) { return __uint_as_float(u << 16); }
__device__ __forceinline__ float bfh(unsigned u) { return __uint_as_float(u & 0xffff0000u); }
__device__ __forceinline__ unsigned short f2bf(float f) {
  unsigned u = __float_as_uint(f);
  u += 0x7fffu + ((u >> 16) & 1u);   // RNE
  return (unsigned short)(u >> 16);
}
__device__ __forceinline__ void load_lds16(const void* g, void* l) {
  __builtin_amdgcn_global_load_lds(
      (const __attribute__((address_space(1))) void*)g,
      (__attribute__((address_space(3))) void*)l, 16, 0, 0);
}

// ---------------- row-normalize + cast to bf16 -------------------------------
__global__ void k_normalize(const float* __restrict__ in, unsigned short* __restrict__ out) {
  const int wv = threadIdx.x >> 6, lane = threadIdx.x & 63;
  const int row = blockIdx.x * 4 + wv;
  const float4 v = ((const float4*)(in + (size_t)row * DFEAT))[lane];
  float ss = v.x * v.x + v.y * v.y + v.z * v.z + v.w * v.w;
#pragma unroll
  for (int off = 32; off; off >>= 1) ss += __shfl_xor(ss, off);
  const float inv = rsqrtf(ss);
  unsigned a = (unsigned)f2bf(v.x * inv) | ((unsigned)f2bf(v.y * inv) << 16);
  unsigned b = (unsigned)f2bf(v.z * inv) | ((unsigned)f2bf(v.w * inv) << 16);
  ((uint2*)(out + (size_t)row * DFEAT))[lane] = make_uint2(a, b);
}

// ---------------- m97-pattern bf16 GEMM: C = A @ B^T -------------------------
// mode 0: out = bf16(acc); mode 1: out = bf16(-acc);
// mode 2: out = bf16(exp((acc - ct[col]) * 20))
__global__ __launch_bounds__(256) void k_gemm_bt(
    const unsigned short* __restrict__ A, const unsigned short* __restrict__ B,
    int ld, int K, unsigned short* __restrict__ out,
    int mode, const float* __restrict__ ct)
{
  __shared__ unsigned short Als[128 * 32];
  __shared__ unsigned short Bls[128 * 32];
  const int tid = threadIdx.x;
  const int w = tid >> 6, lane = tid & 63;
  const int wr = w >> 1, wc = w & 1;                 // 2x2 waves, 64x64 each
  const int mbase = blockIdx.y * 128, nbase = blockIdx.x * 128;

  const f32x4 fz = {0.f, 0.f, 0.f, 0.f};
  f32x4 acc[4][4];
#pragma unroll
  for (int m = 0; m < 4; m++)
#pragma unroll
    for (int n = 0; n < 4; n++) acc[m][n] = fz;

  const int sRow = lane >> 2;            // 0..15
  const int sCol = (lane & 3) * 8;       // 0,8,16,24
  const unsigned short* gA = A + (size_t)(mbase + w * 32 + sRow) * ld + sCol;
  const unsigned short* gB = B + (size_t)(nbase + w * 32 + sRow) * ld + sCol;
  unsigned short* lA0 = &Als[(w * 2 + 0) * 512];
  unsigned short* lA1 = &Als[(w * 2 + 1) * 512];
  unsigned short* lB0 = &Bls[(w * 2 + 0) * 512];
  unsigned short* lB1 = &Bls[(w * 2 + 1) * 512];

  const int rA = lane & 15, kg = (lane >> 4) * 8;

  for (int k0 = 0; k0 < K; k0 += 32) {
    __syncthreads();
    load_lds16(gA + k0, lA0);
    load_lds16(gA + (size_t)16 * ld + k0, lA1);
    load_lds16(gB + k0, lB0);
    load_lds16(gB + (size_t)16 * ld + k0, lB1);
    __syncthreads();
    bf16x8 a[4], b[4];
#pragma unroll
    for (int m = 0; m < 4; m++)
      a[m] = *(const bf16x8*)&Als[(wr * 64 + m * 16 + rA) * 32 + kg];
#pragma unroll
    for (int n = 0; n < 4; n++)
      b[n] = *(const bf16x8*)&Bls[(wc * 64 + n * 16 + rA) * 32 + kg];
#pragma unroll
    for (int m = 0; m < 4; m++)
#pragma unroll
      for (int n = 0; n < 4; n++)
        acc[m][n] = __builtin_amdgcn_mfma_f32_16x16x32_bf16(a[m], b[n], acc[m][n], 0, 0, 0);
  }

  const int crow0 = mbase + wr * 64 + (lane >> 4) * 4;
  const int ccol0 = nbase + wc * 64 + (lane & 15);
#pragma unroll
  for (int m = 0; m < 4; m++) {
#pragma unroll
    for (int n = 0; n < 4; n++) {
      const int col = ccol0 + n * 16;
      const float cv = (mode == 2) ? ct[col] : 0.0f;
#pragma unroll
      for (int r = 0; r < 4; r++) {
        const int row = crow0 + m * 16 + r;
        float val = acc[m][n][r];
        if (mode == 1) val = -val;
        else if (mode == 2) val = __expf((val - cv) * 20.0f);
        out[(size_t)row * N4K + col] = f2bf(val);
      }
    }
  }
}

// ---------------- scalar init ------------------------------------------------
__global__ void k_zero1(float* p) { if (threadIdx.x == 0) *p = 0.0f; }

__global__ void k_setones(float* __restrict__ v) {
  v[blockIdx.x * 256 + threadIdx.x] = 1.0f;
}

__global__ void k_fill_bf16(unsigned short* __restrict__ T, unsigned pattern) {
  const size_t c = (size_t)blockIdx.x * 256 + threadIdx.x;
  ((uint4*)T)[c] = make_uint4(pattern, pattern, pattern, pattern);
}

// ---------------- column stats of S (colsum, colsum^2, global max) -----------
__global__ void k_stats(const unsigned short* __restrict__ S, float* __restrict__ psum,
                        float* __restrict__ psq, float* __restrict__ dmax) {
  const int tid = threadIdx.x;
  const int c0 = blockIdx.x * 2048 + tid * 8;
  const int r0 = blockIdx.y * 128;
  float s[8], q2[8];
#pragma unroll
  for (int e = 0; e < 8; e++) { s[e] = 0.f; q2[e] = 0.f; }
  float mx = -2.0f;
  for (int r = 0; r < 128; r++) {
    const uint4 q = *(const uint4*)&S[(size_t)(r0 + r) * N4K + c0];
    const float f0 = bfl(q.x), f1 = bfh(q.x), f2_ = bfl(q.y), f3 = bfh(q.y);
    const float f4 = bfl(q.z), f5 = bfh(q.z), f6 = bfl(q.w), f7 = bfh(q.w);
    s[0] += f0; q2[0] += f0 * f0; mx = fmaxf(mx, f0);
    s[1] += f1; q2[1] += f1 * f1; mx = fmaxf(mx, f1);
    s[2] += f2_; q2[2] += f2_ * f2_; mx = fmaxf(mx, f2_);
    s[3] += f3; q2[3] += f3 * f3; mx = fmaxf(mx, f3);
    s[4] += f4; q2[4] += f4 * f4; mx = fmaxf(mx, f4);
    s[5] += f5; q2[5] += f5 * f5; mx = fmaxf(mx, f5);
    s[6] += f6; q2[6] += f6 * f6; mx = fmaxf(mx, f6);
    s[7] += f7; q2[7] += f7 * f7; mx = fmaxf(mx, f7);
  }
  float* ps = psum + (size_t)blockIdx.y * N4K + c0;
  float* pq = psq + (size_t)blockIdx.y * N4K + c0;
  *(float4*)ps = make_float4(s[0], s[1], s[2], s[3]);
  *(float4*)(ps + 4) = make_float4(s[4], s[5], s[6], s[7]);
  *(float4*)pq = make_float4(q2[0], q2[1], q2[2], q2[3]);
  *(float4*)(pq + 4) = make_float4(q2[4], q2[5], q2[6], q2[7]);

  __shared__ float red[256];
  red[tid] = mx;
  __syncthreads();
  for (int st = 128; st > 0; st >>= 1) {
    if (tid < st) red[tid] = fmaxf(red[tid], red[tid + st]);
    __syncthreads();
  }
  if (tid == 0) atomicMax((int*)dmax, __float_as_int(fmaxf(red[0], 0.0f)));
}

// mode 0: vecout = c1 = (1+cm)/m ; mode 1: vecout = r2 = (1+2cm+cmsq)/m^2
__global__ void k_statsfinal(const float* __restrict__ psum, const float* __restrict__ psq,
                             const float* __restrict__ dmax, float* __restrict__ cm,
                             float* __restrict__ vecout, int mode) {
  const int j = blockIdx.x * 256 + threadIdx.x;
  float s = 0.f, sq = 0.f;
  for (int c = 0; c < 32; c++) {
    s += psum[(size_t)c * N4K + j];
    sq += psq[(size_t)c * N4K + j];
  }
  const float cmean = s * (1.0f / N4K), cmsq = sq * (1.0f / N4K);
  const float m = 1.0f + *dmax;
  cm[j] = cmean;
  if (mode == 0) vecout[j] = (1.0f + cmean) / m;
  else vecout[j] = (1.0f + 2.0f * cmean + cmsq) / (m * m);
}

// out_ij = bf16( (S_ij - cm_j) * sc / (1+max) )
__global__ void k_center(const unsigned short* __restrict__ S, const float* __restrict__ cm,
                         const float* __restrict__ dmax, unsigned short* __restrict__ out,
                         float sc) {
  const int c = blockIdx.x * 256 + threadIdx.x;
  const int row = c >> 9;
  const int col0 = (c & 511) * 8;
  const float inv = sc / (1.0f + *dmax);
  const uint4 q = *(const uint4*)&S[(size_t)row * N4K + col0];
  const float4 ca = *(const float4*)&cm[col0];
  const float4 cb = *(const float4*)&cm[col0 + 4];
  unsigned r0 = (unsigned)f2bf((bfl(q.x) - ca.x) * inv) | ((unsigned)f2bf((bfh(q.x) - ca.y) * inv) << 16);
  unsigned r1 = (unsigned)f2bf((bfl(q.y) - ca.z) * inv) | ((unsigned)f2bf((bfh(q.y) - ca.w) * inv) << 16);
  unsigned r2_ = (unsigned)f2bf((bfl(q.z) - cb.x) * inv) | ((unsigned)f2bf((bfh(q.z) - cb.y) * inv) << 16);
  unsigned r3 = (unsigned)f2bf((bfl(q.w) - cb.z) * inv) | ((unsigned)f2bf((bfh(q.w) - cb.w) * inv) << 16);
  *(uint4*)&out[(size_t)row * N4K + col0] = make_uint4(r0, r1, r2_, r3);
}

// ---------------- row matvec (ct path): one wave per row ---------------------
// mode 2: out = r2[row] - sum
__global__ void k_rowmv(const unsigned short* __restrict__ M, const float* __restrict__ x,
                        float* __restrict__ out, int mode, const float* __restrict__ r2) {
  const int wv = threadIdx.x >> 6, lane = threadIdx.x & 63;
  const int row = blockIdx.x * 4 + wv;
  const unsigned short* r = M + (size_t)row * N4K;
  float acc = 0.f;
#pragma unroll
  for (int p = 0; p < 8; p++) {
    const int j0 = p * 512 + lane * 8;
    const uint4 q = *(const uint4*)&r[j0];
    const float4 xa = *(const float4*)&x[j0];
    const float4 xb = *(const float4*)&x[j0 + 4];
    acc += bfl(q.x) * xa.x + bfh(q.x) * xa.y + bfl(q.y) * xa.z + bfh(q.y) * xa.w
         + bfl(q.z) * xb.x + bfh(q.z) * xb.y + bfl(q.w) * xb.z + bfh(q.w) * xb.w;
  }
#pragma unroll
  for (int off = 32; off; off >>= 1) acc += __shfl_xor(acc, off);
  if (lane == 0) {
    if (mode == 0) out[row] = acc;
    else if (mode == 1) out[row] = P_UNIF / acc;
    else out[row] = r2[row] - acc;
  }
}

// ---------------- column matvec (ct path), 128 blocks ------------------------
__global__ void k_colmv(const unsigned short* __restrict__ M, const float* __restrict__ x,
                        float* __restrict__ partials) {
  const int tid = threadIdx.x;
  const int c0 = blockIdx.x * 1024 + tid * 4;
  const int r0 = blockIdx.y * 128;
  float a0 = 0, a1 = 0, a2 = 0, a3 = 0;
  for (int r = 0; r < 128; r++) {
    const float xv = x[r0 + r];
    const uint2 q = *(const uint2*)&M[(size_t)(r0 + r) * N4K + c0];
    a0 += xv * bfl(q.x); a1 += xv * bfh(q.x);
    a2 += xv * bfl(q.y); a3 += xv * bfh(q.y);
  }
  float* p = partials + (size_t)blockIdx.y * N4K + c0;
  *(float4*)p = make_float4(a0, a1, a2, a3);
}

// mode 0: out = sum
__global__ void k_colreduce(const float* __restrict__ partials, float* __restrict__ out,
                            int mode) {
  const int j = blockIdx.x * 256 + threadIdx.x;
  float s = 0.f;
  for (int c = 0; c < 32; c++) s += partials[(size_t)c * N4K + j];
  out[j] = (mode == 0) ? s : P_UNIF / s;
}

// ---------------- fused Sinkhorn iteration -----------------------------------
// One pass over K: u = p/(K v) for this block's 8 rows, then partial column
// sums of K^T u (rows re-read L2-hot). grid 512 x 256 threads.
__global__ __launch_bounds__(256) void k_sink(
    const unsigned short* __restrict__ Km, const float* __restrict__ v,
    float* __restrict__ u, float* __restrict__ partials)
{
  __shared__ float vs[4096];
  __shared__ float us[8];
  const int tid = threadIdx.x;
  {
    const float4* vg = (const float4*)v;
    float4* vl = (float4*)vs;
#pragma unroll
    for (int i = 0; i < 4; i++) vl[tid + 256 * i] = vg[tid + 256 * i];
  }
  __syncthreads();
  const int wv = tid >> 6, lane = tid & 63;
  const int row0 = blockIdx.x * 8 + wv * 2;
  const unsigned short* rA = Km + (size_t)row0 * N4K;
  const unsigned short* rB = rA + N4K;
  float accA = 0.f, accB = 0.f;
#pragma unroll
  for (int p = 0; p < 8; p++) {
    const int j0 = p * 512 + lane * 8;
    const uint4 qa = *(const uint4*)&rA[j0];
    const uint4 qb = *(const uint4*)&rB[j0];
    const float4 xa = *(const float4*)&vs[j0];
    const float4 xb = *(const float4*)&vs[j0 + 4];
    accA += bfl(qa.x) * xa.x + bfh(qa.x) * xa.y + bfl(qa.y) * xa.z + bfh(qa.y) * xa.w
          + bfl(qa.z) * xb.x + bfh(qa.z) * xb.y + bfl(qa.w) * xb.z + bfh(qa.w) * xb.w;
    accB += bfl(qb.x) * xa.x + bfh(qb.x) * xa.y + bfl(qb.y) * xa.z + bfh(qb.y) * xa.w
          + bfl(qb.z) * xb.x + bfh(qb.z) * xb.y + bfl(qb.w) * xb.z + bfh(qb.w) * xb.w;
  }
#pragma unroll
  for (int off = 32; off; off >>= 1) {
    accA += __shfl_xor(accA, off);
    accB += __shfl_xor(accB, off);
  }
  if (lane == 0) {
    const float uA = P_UNIF / accA, uB = P_UNIF / accB;
    u[row0] = uA; u[row0 + 1] = uB;
    us[wv * 2] = uA; us[wv * 2 + 1] = uB;
  }
  __syncthreads();
  // phase 2: thread owns 16 columns; 8 rows (L2-hot)
  const int c0 = tid * 16;
  float acc[16];
#pragma unroll
  for (int e = 0; e < 16; e++) acc[e] = 0.f;
  const unsigned short* base = Km + (size_t)blockIdx.x * 8 * N4K + c0;
#pragma unroll
  for (int r = 0; r < 8; r++) {
    const float ur = us[r];
    const uint4 qa = *(const uint4*)&base[(size_t)r * N4K];
    const uint4 qb = *(const uint4*)&base[(size_t)r * N4K + 8];
    acc[0] += ur * bfl(qa.x); acc[1] += ur * bfh(qa.x);
    acc[2] += ur * bfl(qa.y); acc[3] += ur * bfh(qa.y);
    acc[4] += ur * bfl(qa.z); acc[5] += ur * bfh(qa.z);
    acc[6] += ur * bfl(qa.w); acc[7] += ur * bfh(qa.w);
    acc[8]  += ur * bfl(qb.x); acc[9]  += ur * bfh(qb.x);
    acc[10] += ur * bfl(qb.y); acc[11] += ur * bfh(qb.y);
    acc[12] += ur * bfl(qb.z); acc[13] += ur * bfh(qb.z);
    acc[14] += ur * bfl(qb.w); acc[15] += ur * bfh(qb.w);
  }
  float* pp = partials + (size_t)blockIdx.x * N4K + c0;
  *(float4*)pp = make_float4(acc[0], acc[1], acc[2], acc[3]);
  *(float4*)(pp + 4) = make_float4(acc[4], acc[5], acc[6], acc[7]);
  *(float4*)(pp + 8) = make_float4(acc[8], acc[9], acc[10], acc[11]);
  *(float4*)(pp + 12) = make_float4(acc[12], acc[13], acc[14], acc[15]);
}

// v_j = q / sum_{b<512} partials[b][j].  grid 128 x 256; block covers 32 cols.
__global__ void k_sinkfin(const float* __restrict__ partials, float* __restrict__ v) {
  __shared__ float red[8][32];
  const int tid = threadIdx.x;
  const int c = (blockIdx.x << 5) + (tid & 31);
  const int s = tid >> 5;                     // 0..7
  float acc = 0.f;
  const float* p = partials + (size_t)s * 64 * N4K + c;
#pragma unroll 8
  for (int b = 0; b < 64; b++) acc += p[(size_t)b * N4K];
  red[s][tid & 31] = acc;
  __syncthreads();
  if (s == 0) {
    float t = red[0][tid] + red[1][tid] + red[2][tid] + red[3][tid]
            + red[4][tid] + red[5][tid] + red[6][tid] + red[7][tid];
    v[c] = P_UNIF / t;
  }
}

// ---------------- T = u (.) K (.) v, in place --------------------------------
__global__ void k_scaleT(unsigned short* __restrict__ K, const float* __restrict__ u,
                         const float* __restrict__ v) {
  const int c = blockIdx.x * 256 + threadIdx.x;
  const int row = c >> 9;
  const int col0 = (c & 511) * 8;
  const float ur = u[row];
  unsigned short* p = K + (size_t)row * N4K + col0;
  const uint4 q = *(const uint4*)p;
  const float4 va = *(const float4*)&v[col0];
  const float4 vb = *(const float4*)&v[col0 + 4];
  unsigned r0 = (unsigned)f2bf(ur * bfl(q.x) * va.x) | ((unsigned)f2bf(ur * bfh(q.x) * va.y) << 16);
  unsigned r1 = (unsigned)f2bf(ur * bfl(q.y) * va.z) | ((unsigned)f2bf(ur * bfh(q.y) * va.w) << 16);
  unsigned r2_ = (unsigned)f2bf(ur * bfl(q.z) * vb.x) | ((unsigned)f2bf(ur * bfh(q.z) * vb.y) << 16);
  unsigned r3 = (unsigned)f2bf(ur * bfl(q.w) * vb.z) | ((unsigned)f2bf(ur * bfh(q.w) * vb.w) << 16);
  *(uint4*)p = make_uint4(r0, r1, r2_, r3);
}

// ---------------- loss = -sum log(u_i K_ii v_i + 1e-10) ----------------------
__global__ void k_loss(const unsigned short* __restrict__ K, const float* __restrict__ u,
                       const float* __restrict__ v, float* __restrict__ out) {
  const int tid = threadIdx.x;
  float acc = 0.f;
  for (int i = tid; i < N4K; i += 256) {
    const float d = u[i] * bfl((unsigned)K[(size_t)i * (N4K + 1)]) * v[i];
    acc += logf(d + 1e-10f);
  }
  __shared__ float red[256];
  red[tid] = acc;
  __syncthreads();
  for (int st = 128; st > 0; st >>= 1) {
    if (tid < st) red[tid] += red[tid + st];
    __syncthreads();
  }
  if (tid == 0) out[0] = -red[0];
}

// ============================================================================
extern "C" void kernel_launch(void* const* d_in, const int* in_sizes, int n_in,
                              void* d_out, int out_size, void* d_ws, size_t ws_size,
                              hipStream_t stream) {
  const float* f1 = (const float*)d_in[0];
  const float* f2 = (const float*)d_in[1];
  float* out = (float*)d_out;

  char* w = (char*)d_ws;
  const size_t NN = (size_t)N4K * N4K;
  unsigned short* X1 = (unsigned short*)w;   w += (size_t)N4K * DFEAT * 2;
  unsigned short* X2 = (unsigned short*)w;   w += (size_t)N4K * DFEAT * 2;
  unsigned short* C1h = (unsigned short*)w;  w += NN * 2;   // column-centered C1 (bf16)
  unsigned short* H2h = (unsigned short*)w;  w += NN * 2;   // column-centered 2*C2 (bf16)
  unsigned short* Sbuf = (unsigned short*)w; w += NN * 2;   // S scratch / Aprime / sink partials
  unsigned short* T0 = (unsigned short*)w;   w += NN * 2;
  unsigned short* T1 = (unsigned short*)w;   w += NN * 2;
  float* ps1 = (float*)w;  w += (size_t)32 * N4K * 4;
  float* ps2 = (float*)w;  w += (size_t)32 * N4K * 4;
  float* uvec = (float*)w; w += N4K * 4;
  float* vvec = (float*)w; w += N4K * 4;
  float* wvec = (float*)w; w += N4K * 4;
  float* ctv = (float*)w;  w += N4K * 4;
  float* r2v = (float*)w;  w += N4K * 4;
  float* c1v = (float*)w;  w += N4K * 4;
  float* cmv = (float*)w;  w += N4K * 4;
  float* dmax = (float*)w; w += 256;

  const dim3 b256(256);
  const dim3 gGemm(32, 32);
  const dim3 gStat(2, 32);
  const dim3 gCol(4, 32);

  k_normalize<<<1024, b256, 0, stream>>>(f1, X1);
  k_normalize<<<1024, b256, 0, stream>>>(f2, X2);

  // ---- cost matrix 1: S = -X1 X1^T ; c1 = colmean; C1h = centered ----
  k_gemm_bt<<<gGemm, b256, 0, stream>>>(X1, X1, DFEAT, DFEAT, Sbuf, 1, nullptr);
  k_zero1<<<1, 64, 0, stream>>>(dmax);
  k_stats<<<gStat, b256, 0, stream>>>(Sbuf, ps1, ps2, dmax);
  k_statsfinal<<<16, b256, 0, stream>>>(ps1, ps2, dmax, cmv, c1v, 0);
  k_center<<<8192, b256, 0, stream>>>(Sbuf, cmv, dmax, C1h, 1.0f);

  // ---- cost matrix 2: r2 = rowmean(C2^2) ; H2h = centered 2*C2 ----
  k_gemm_bt<<<gGemm, b256, 0, stream>>>(X2, X2, DFEAT, DFEAT, Sbuf, 1, nullptr);
  k_zero1<<<1, 64, 0, stream>>>(dmax);
  k_stats<<<gStat, b256, 0, stream>>>(Sbuf, ps1, ps2, dmax);
  k_statsfinal<<<16, b256, 0, stream>>>(ps1, ps2, dmax, cmv, r2v, 1);
  k_center<<<8192, b256, 0, stream>>>(Sbuf, cmv, dmax, H2h, 2.0f);

  // ---- T = outer(p,q) = 2^-24 (bf16 0x3380, exact) ----
  k_fill_bf16<<<8192, b256, 0, stream>>>(T0, 0x33803380u);

  unsigned short* Tc = T0;
  unsigned short* Ko = T1;
  for (int it = 0; it < 5; it++) {
    // Aprime = H2h @ Tc^T
    k_gemm_bt<<<gGemm, b256, 0, stream>>>(H2h, Tc, N4K, N4K, Sbuf, 0, nullptr);
    // w = Tc^T c1 ; ct_j = r2_j - (H2h w)_j
    k_colmv<<<gCol, b256, 0, stream>>>(Tc, c1v, ps1);
    k_colreduce<<<16, b256, 0, stream>>>(ps1, wvec, 0);
    k_rowmv<<<1024, b256, 0, stream>>>(H2h, wvec, ctv, 2, r2v);
    // K = exp((C1h @ Aprime^T - ct_j) / eps)
    k_gemm_bt<<<gGemm, b256, 0, stream>>>(C1h, Sbuf, N4K, N4K, Ko, 2, ctv);
    // Sinkhorn: 20 x { u = p/(K v) ; v = q/(K^T u) }, v0 = 1; Sbuf is free here.
    float* sp = (float*)Sbuf;   // 512 x 4096 fp32 partials (8 MB < 33.5 MB)
    k_setones<<<16, b256, 0, stream>>>(vvec);
    for (int s = 0; s < 20; s++) {
      k_sink<<<512, b256, 0, stream>>>(Ko, vvec, uvec, sp);
      k_sinkfin<<<128, b256, 0, stream>>>(sp, vvec);
    }
    if (it < 4) {
      k_scaleT<<<8192, b256, 0, stream>>>(Ko, uvec, vvec);  // K -> T in place
      unsigned short* tmp = Tc; Tc = Ko; Ko = tmp;
    }
  }
  k_loss<<<1, b256, 0, stream>>>(Ko, uvec, vvec, out);
}

// Round 5
// 2490.529 us; speedup vs baseline: 1.8878x; 1.5350x over previous
//
#include <hip/hip_runtime.h>

#define N4K 4096
#define DFEAT 256
constexpr float P_UNIF = 1.0f / 4096.0f;

typedef __attribute__((ext_vector_type(8))) short bf16x8;
typedef __attribute__((ext_vector_type(4))) float f32x4;

__device__ __forceinline__ float bfl(unsigned u) { return __uint_as_float(u << 16); }
__device__ __forceinline__ float bfh(unsigned u) { return __uint_as_float(u & 0xffff0000u); }
__device__ __forceinline__ unsigned short f2bf(float f) {
  unsigned u = __float_as_uint(f);
  u += 0x7fffu + ((u >> 16) & 1u);   // RNE
  return (unsigned short)(u >> 16);
}
__device__ __forceinline__ void load_lds16(const void* g, void* l) {
  __builtin_amdgcn_global_load_lds(
      (const __attribute__((address_space(1))) void*)g,
      (__attribute__((address_space(3))) void*)l, 16, 0, 0);
}

// ---------------- row-normalize + cast to bf16 -------------------------------
__global__ void k_normalize(const float* __restrict__ in, unsigned short* __restrict__ out) {
  const int wv = threadIdx.x >> 6, lane = threadIdx.x & 63;
  const int row = blockIdx.x * 4 + wv;
  const float4 v = ((const float4*)(in + (size_t)row * DFEAT))[lane];
  float ss = v.x * v.x + v.y * v.y + v.z * v.z + v.w * v.w;
#pragma unroll
  for (int off = 32; off; off >>= 1) ss += __shfl_xor(ss, off);
  const float inv = rsqrtf(ss);
  unsigned a = (unsigned)f2bf(v.x * inv) | ((unsigned)f2bf(v.y * inv) << 16);
  unsigned b = (unsigned)f2bf(v.z * inv) | ((unsigned)f2bf(v.w * inv) << 16);
  ((uint2*)(out + (size_t)row * DFEAT))[lane] = make_uint2(a, b);
}

// ---------------- bf16 transpose [R x C] -> [C x R], 64x64 tiles -------------
// grid (C/64, R/64), 256 threads
__global__ void k_transpose(const unsigned short* __restrict__ in,
                            unsigned short* __restrict__ out, int R, int C) {
  __shared__ unsigned short t[64][65];
  const int tid = threadIdx.x;
  const int tx = tid & 63, ty = tid >> 6;
  const int c0 = blockIdx.x * 64, r0 = blockIdx.y * 64;
#pragma unroll
  for (int k = 0; k < 16; k++) {
    const int r = ty * 16 + k;
    t[r][tx] = in[(size_t)(r0 + r) * C + c0 + tx];
  }
  __syncthreads();
#pragma unroll
  for (int k = 0; k < 16; k++) {
    const int r = ty * 16 + k;
    out[(size_t)(c0 + r) * R + r0 + tx] = t[tx][r];
  }
}

// ---------------- m97-pattern bf16 GEMM: C = A @ B^T -------------------------
// A rows from blockIdx.y*128, B rows from blockIdx.x*128, both ld-strided,
// k in [blockIdx.z*kChunk, +kChunk).
// mode 0: bf16 out[row*ldo+col] = acc
// mode 1: bf16 out = -acc                      (Gram -> S = -G)
// mode 2: bf16 out = exp(sArg*acc - ctE[col]), sArg = 40/((1+dm1)(1+dm2))
// mode 3: fp32 outf[(z*Mrows + row)*ldo + col] = acc   (K-split partials)
__global__ __launch_bounds__(256) void k_gemm_bt(
    const unsigned short* __restrict__ A, const unsigned short* __restrict__ B,
    int ld, int kChunk, unsigned short* __restrict__ out, float* __restrict__ outf,
    int ldo, int mode, const float* __restrict__ ctE,
    const float* __restrict__ dm1, const float* __restrict__ dm2)
{
  __shared__ unsigned short Als[128 * 32];
  __shared__ unsigned short Bls[128 * 32];
  const int tid = threadIdx.x;
  const int w = tid >> 6, lane = tid & 63;
  const int wr = w >> 1, wc = w & 1;                 // 2x2 waves, 64x64 each
  const int mbase = blockIdx.y * 128, nbase = blockIdx.x * 128;
  const int kBase = blockIdx.z * kChunk;

  const f32x4 fz = {0.f, 0.f, 0.f, 0.f};
  f32x4 acc[4][4];
#pragma unroll
  for (int m = 0; m < 4; m++)
#pragma unroll
    for (int n = 0; n < 4; n++) acc[m][n] = fz;

  const int sRow = lane >> 2;            // 0..15
  const int sCol = (lane & 3) * 8;       // 0,8,16,24
  const unsigned short* gA = A + (size_t)(mbase + w * 32 + sRow) * ld + sCol;
  const unsigned short* gB = B + (size_t)(nbase + w * 32 + sRow) * ld + sCol;
  unsigned short* lA0 = &Als[(w * 2 + 0) * 512];
  unsigned short* lA1 = &Als[(w * 2 + 1) * 512];
  unsigned short* lB0 = &Bls[(w * 2 + 0) * 512];
  unsigned short* lB1 = &Bls[(w * 2 + 1) * 512];

  const int rA = lane & 15, kg = (lane >> 4) * 8;

  for (int k0 = kBase; k0 < kBase + kChunk; k0 += 32) {
    __syncthreads();
    load_lds16(gA + k0, lA0);
    load_lds16(gA + (size_t)16 * ld + k0, lA1);
    load_lds16(gB + k0, lB0);
    load_lds16(gB + (size_t)16 * ld + k0, lB1);
    __syncthreads();
    bf16x8 a[4], b[4];
#pragma unroll
    for (int m = 0; m < 4; m++)
      a[m] = *(const bf16x8*)&Als[(wr * 64 + m * 16 + rA) * 32 + kg];
#pragma unroll
    for (int n = 0; n < 4; n++)
      b[n] = *(const bf16x8*)&Bls[(wc * 64 + n * 16 + rA) * 32 + kg];
#pragma unroll
    for (int m = 0; m < 4; m++)
#pragma unroll
      for (int n = 0; n < 4; n++)
        acc[m][n] = __builtin_amdgcn_mfma_f32_16x16x32_bf16(a[m], b[n], acc[m][n], 0, 0, 0);
  }

  // C/D layout: col = lane&15, row = (lane>>4)*4 + r   [m89-verified]
  const int crow0 = mbase + wr * 64 + (lane >> 4) * 4;
  const int ccol0 = nbase + wc * 64 + (lane & 15);
  float sArg = 0.f;
  if (mode == 2) sArg = 40.0f / ((1.0f + *dm1) * (1.0f + *dm2));
#pragma unroll
  for (int m = 0; m < 4; m++) {
#pragma unroll
    for (int n = 0; n < 4; n++) {
      const int col = ccol0 + n * 16;
      const float cv = (mode == 2) ? ctE[col] : 0.0f;
#pragma unroll
      for (int r = 0; r < 4; r++) {
        const int row = crow0 + m * 16 + r;
        float val = acc[m][n][r];
        if (mode == 3) {
          outf[((size_t)blockIdx.z * (gridDim.y * 128) + row) * ldo + col] = val;
        } else {
          if (mode == 1) val = -val;
          else if (mode == 2) val = __expf(fmaf(sArg, val, -cv));
          out[(size_t)row * ldo + col] = f2bf(val);
        }
      }
    }
  }
}

// ---------------- scalar init ------------------------------------------------
__global__ void k_zero1(float* p) { if (threadIdx.x == 0) *p = 0.0f; }

__global__ void k_setones(float* __restrict__ v) {
  v[blockIdx.x * 256 + threadIdx.x] = 1.0f;
}

__global__ void k_fill_bf16(unsigned short* __restrict__ T, unsigned pattern) {
  const size_t c = (size_t)blockIdx.x * 256 + threadIdx.x;
  ((uint4*)T)[c] = make_uint4(pattern, pattern, pattern, pattern);
}

// ---------------- column stats of S (colsum, colsum^2, global max) -----------
__global__ void k_stats(const unsigned short* __restrict__ S, float* __restrict__ psum,
                        float* __restrict__ psq, float* __restrict__ dmax) {
  const int tid = threadIdx.x;
  const int c0 = blockIdx.x * 2048 + tid * 8;
  const int r0 = blockIdx.y * 128;
  float s[8], q2[8];
#pragma unroll
  for (int e = 0; e < 8; e++) { s[e] = 0.f; q2[e] = 0.f; }
  float mx = -2.0f;
  for (int r = 0; r < 128; r++) {
    const uint4 q = *(const uint4*)&S[(size_t)(r0 + r) * N4K + c0];
    const float f0 = bfl(q.x), f1 = bfh(q.x), f2_ = bfl(q.y), f3 = bfh(q.y);
    const float f4 = bfl(q.z), f5 = bfh(q.z), f6 = bfl(q.w), f7 = bfh(q.w);
    s[0] += f0; q2[0] += f0 * f0; mx = fmaxf(mx, f0);
    s[1] += f1; q2[1] += f1 * f1; mx = fmaxf(mx, f1);
    s[2] += f2_; q2[2] += f2_ * f2_; mx = fmaxf(mx, f2_);
    s[3] += f3; q2[3] += f3 * f3; mx = fmaxf(mx, f3);
    s[4] += f4; q2[4] += f4 * f4; mx = fmaxf(mx, f4);
    s[5] += f5; q2[5] += f5 * f5; mx = fmaxf(mx, f5);
    s[6] += f6; q2[6] += f6 * f6; mx = fmaxf(mx, f6);
    s[7] += f7; q2[7] += f7 * f7; mx = fmaxf(mx, f7);
  }
  float* ps = psum + (size_t)blockIdx.y * N4K + c0;
  float* pq = psq + (size_t)blockIdx.y * N4K + c0;
  *(float4*)ps = make_float4(s[0], s[1], s[2], s[3]);
  *(float4*)(ps + 4) = make_float4(s[4], s[5], s[6], s[7]);
  *(float4*)pq = make_float4(q2[0], q2[1], q2[2], q2[3]);
  *(float4*)(pq + 4) = make_float4(q2[4], q2[5], q2[6], q2[7]);

  __shared__ float red[256];
  red[tid] = mx;
  __syncthreads();
  for (int st = 128; st > 0; st >>= 1) {
    if (tid < st) red[tid] = fmaxf(red[tid], red[tid + st]);
    __syncthreads();
  }
  if (tid == 0) atomicMax((int*)dmax, __float_as_int(fmaxf(red[0], 0.0f)));
}

// ctE_j = [ (1-2*g2_j+s2_j)/m2^2 + (2/(m1*m2))*g2_j ] / eps   (stats are of S=-G2)
__global__ void k_ctfinal(const float* __restrict__ psum, const float* __restrict__ psq,
                          const float* __restrict__ dm1p, const float* __restrict__ dm2p,
                          float* __restrict__ ctE) {
  const int j = blockIdx.x * 256 + threadIdx.x;
  float s = 0.f, sq = 0.f;
  for (int c = 0; c < 32; c++) {
    s += psum[(size_t)c * N4K + j];
    sq += psq[(size_t)c * N4K + j];
  }
  const float g2 = -s * (1.0f / N4K);     // colmean of G2
  const float s2 = sq * (1.0f / N4K);     // colmean of G2^2
  const float m1 = 1.0f + *dm1p, m2 = 1.0f + *dm2p;
  ctE[j] = ((1.0f - 2.0f * g2 + s2) / (m2 * m2) + (2.0f / (m1 * m2)) * g2) * 20.0f;
}

// ---------------- reduce 8 K-chunk partials of Y and transpose ---------------
// Yp: [8][4096][256] fp32 -> Yt: [256][4096] bf16.  grid (64, 4), 256 thr.
__global__ void k_redY(const float* __restrict__ Yp, unsigned short* __restrict__ Yt) {
  __shared__ float t[64][65];
  const int tid = threadIdx.x;
  const int tx = tid & 63, ty = tid >> 6;
  const int r0 = blockIdx.x * 64, c0 = blockIdx.y * 64;
#pragma unroll
  for (int k = 0; k < 16; k++) {
    const int r = ty * 16 + k;
    const size_t off = (size_t)(r0 + r) * 256 + c0 + tx;
    float s = 0.f;
#pragma unroll
    for (int z = 0; z < 8; z++) s += Yp[(size_t)z * (N4K * 256) + off];
    t[r][tx] = s;
  }
  __syncthreads();
#pragma unroll
  for (int k = 0; k < 16; k++) {
    const int r = ty * 16 + k;
    Yt[(size_t)(c0 + r) * N4K + r0 + tx] = f2bf(t[tx][r]);
  }
}

// ---------------- reduce 16 K-chunk partials of PT ---------------------------
// Pp: [16][256][256] fp32 -> PTb [256][256] bf16.  grid 256, 256 thr.
__global__ void k_redPT(const float* __restrict__ Pp, unsigned short* __restrict__ PTb) {
  const int idx = blockIdx.x * 256 + threadIdx.x;
  float s = 0.f;
#pragma unroll
  for (int z = 0; z < 16; z++) s += Pp[z * 65536 + idx];
  PTb[idx] = f2bf(s);
}

// ---------------- fused Sinkhorn iteration -----------------------------------
__global__ __launch_bounds__(256) void k_sink(
    const unsigned short* __restrict__ Km, const float* __restrict__ v,
    float* __restrict__ u, float* __restrict__ partials)
{
  __shared__ float vs[4096];
  __shared__ float us[8];
  const int tid = threadIdx.x;
  {
    const float4* vg = (const float4*)v;
    float4* vl = (float4*)vs;
#pragma unroll
    for (int i = 0; i < 4; i++) vl[tid + 256 * i] = vg[tid + 256 * i];
  }
  __syncthreads();
  const int wv = tid >> 6, lane = tid & 63;
  const int row0 = blockIdx.x * 8 + wv * 2;
  const unsigned short* rA = Km + (size_t)row0 * N4K;
  const unsigned short* rB = rA + N4K;
  float accA = 0.f, accB = 0.f;
#pragma unroll
  for (int p = 0; p < 8; p++) {
    const int j0 = p * 512 + lane * 8;
    const uint4 qa = *(const uint4*)&rA[j0];
    const uint4 qb = *(const uint4*)&rB[j0];
    const float4 xa = *(const float4*)&vs[j0];
    const float4 xb = *(const float4*)&vs[j0 + 4];
    accA += bfl(qa.x) * xa.x + bfh(qa.x) * xa.y + bfl(qa.y) * xa.z + bfh(qa.y) * xa.w
          + bfl(qa.z) * xb.x + bfh(qa.z) * xb.y + bfl(qa.w) * xb.z + bfh(qa.w) * xb.w;
    accB += bfl(qb.x) * xa.x + bfh(qb.x) * xa.y + bfl(qb.y) * xa.z + bfh(qb.y) * xa.w
          + bfl(qb.z) * xb.x + bfh(qb.z) * xb.y + bfl(qb.w) * xb.z + bfh(qb.w) * xb.w;
  }
#pragma unroll
  for (int off = 32; off; off >>= 1) {
    accA += __shfl_xor(accA, off);
    accB += __shfl_xor(accB, off);
  }
  if (lane == 0) {
    const float uA = P_UNIF / accA, uB = P_UNIF / accB;
    u[row0] = uA; u[row0 + 1] = uB;
    us[wv * 2] = uA; us[wv * 2 + 1] = uB;
  }
  __syncthreads();
  const int c0 = tid * 16;
  float acc[16];
#pragma unroll
  for (int e = 0; e < 16; e++) acc[e] = 0.f;
  const unsigned short* base = Km + (size_t)blockIdx.x * 8 * N4K + c0;
#pragma unroll
  for (int r = 0; r < 8; r++) {
    const float ur = us[r];
    const uint4 qa = *(const uint4*)&base[(size_t)r * N4K];
    const uint4 qb = *(const uint4*)&base[(size_t)r * N4K + 8];
    acc[0] += ur * bfl(qa.x); acc[1] += ur * bfh(qa.x);
    acc[2] += ur * bfl(qa.y); acc[3] += ur * bfh(qa.y);
    acc[4] += ur * bfl(qa.z); acc[5] += ur * bfh(qa.z);
    acc[6] += ur * bfl(qa.w); acc[7] += ur * bfh(qa.w);
    acc[8]  += ur * bfl(qb.x); acc[9]  += ur * bfh(qb.x);
    acc[10] += ur * bfl(qb.y); acc[11] += ur * bfh(qb.y);
    acc[12] += ur * bfl(qb.z); acc[13] += ur * bfh(qb.z);
    acc[14] += ur * bfl(qb.w); acc[15] += ur * bfh(qb.w);
  }
  float* pp = partials + (size_t)blockIdx.x * N4K + c0;
  *(float4*)pp = make_float4(acc[0], acc[1], acc[2], acc[3]);
  *(float4*)(pp + 4) = make_float4(acc[4], acc[5], acc[6], acc[7]);
  *(float4*)(pp + 8) = make_float4(acc[8], acc[9], acc[10], acc[11]);
  *(float4*)(pp + 12) = make_float4(acc[12], acc[13], acc[14], acc[15]);
}

__global__ void k_sinkfin(const float* __restrict__ partials, float* __restrict__ v) {
  __shared__ float red[8][32];
  const int tid = threadIdx.x;
  const int c = (blockIdx.x << 5) + (tid & 31);
  const int s = tid >> 5;
  float acc = 0.f;
  const float* p = partials + (size_t)s * 64 * N4K + c;
#pragma unroll 8
  for (int b = 0; b < 64; b++) acc += p[(size_t)b * N4K];
  red[s][tid & 31] = acc;
  __syncthreads();
  if (s == 0) {
    float t = red[0][tid] + red[1][tid] + red[2][tid] + red[3][tid]
            + red[4][tid] + red[5][tid] + red[6][tid] + red[7][tid];
    v[c] = P_UNIF / t;
  }
}

// ---------------- T = u (.) K (.) v, in place --------------------------------
__global__ void k_scaleT(unsigned short* __restrict__ K, const float* __restrict__ u,
                         const float* __restrict__ v) {
  const int c = blockIdx.x * 256 + threadIdx.x;
  const int row = c >> 9;
  const int col0 = (c & 511) * 8;
  const float ur = u[row];
  unsigned short* p = K + (size_t)row * N4K + col0;
  const uint4 q = *(const uint4*)p;
  const float4 va = *(const float4*)&v[col0];
  const float4 vb = *(const float4*)&v[col0 + 4];
  unsigned r0 = (unsigned)f2bf(ur * bfl(q.x) * va.x) | ((unsigned)f2bf(ur * bfh(q.x) * va.y) << 16);
  unsigned r1 = (unsigned)f2bf(ur * bfl(q.y) * va.z) | ((unsigned)f2bf(ur * bfh(q.y) * va.w) << 16);
  unsigned r2_ = (unsigned)f2bf(ur * bfl(q.z) * vb.x) | ((unsigned)f2bf(ur * bfh(q.z) * vb.y) << 16);
  unsigned r3 = (unsigned)f2bf(ur * bfl(q.w) * vb.z) | ((unsigned)f2bf(ur * bfh(q.w) * vb.w) << 16);
  *(uint4*)p = make_uint4(r0, r1, r2_, r3);
}

// ---------------- loss = -sum log(u_i K_ii v_i + 1e-10) ----------------------
__global__ void k_loss(const unsigned short* __restrict__ K, const float* __restrict__ u,
                       const float* __restrict__ v, float* __restrict__ out) {
  const int tid = threadIdx.x;
  float acc = 0.f;
  for (int i = tid; i < N4K; i += 256) {
    const float d = u[i] * bfl((unsigned)K[(size_t)i * (N4K + 1)]) * v[i];
    acc += logf(d + 1e-10f);
  }
  __shared__ float red[256];
  red[tid] = acc;
  __syncthreads();
  for (int st = 128; st > 0; st >>= 1) {
    if (tid < st) red[tid] += red[tid + st];
    __syncthreads();
  }
  if (tid == 0) out[0] = -red[0];
}

// ============================================================================
extern "C" void kernel_launch(void* const* d_in, const int* in_sizes, int n_in,
                              void* d_out, int out_size, void* d_ws, size_t ws_size,
                              hipStream_t stream) {
  const float* f1 = (const float*)d_in[0];
  const float* f2 = (const float*)d_in[1];
  float* out = (float*)d_out;

  char* w = (char*)d_ws;
  const size_t NN = (size_t)N4K * N4K;
  unsigned short* X1 = (unsigned short*)w;   w += (size_t)N4K * DFEAT * 2;
  unsigned short* X2 = (unsigned short*)w;   w += (size_t)N4K * DFEAT * 2;
  unsigned short* X1t = (unsigned short*)w;  w += (size_t)N4K * DFEAT * 2;
  unsigned short* X2t = (unsigned short*)w;  w += (size_t)N4K * DFEAT * 2;
  unsigned short* Zb = (unsigned short*)w;   w += (size_t)N4K * DFEAT * 2;
  unsigned short* Yt = (unsigned short*)w;   w += (size_t)N4K * DFEAT * 2;
  unsigned short* PTb = (unsigned short*)w;  w += (size_t)DFEAT * DFEAT * 2;
  unsigned short* Sbuf = (unsigned short*)w; w += NN * 2;   // S / Y-partials / sink partials
  unsigned short* T0 = (unsigned short*)w;   w += NN * 2;
  unsigned short* T1 = (unsigned short*)w;   w += NN * 2;
  float* Pp = (float*)w;   w += (size_t)16 * DFEAT * DFEAT * 4;
  float* ps1 = (float*)w;  w += (size_t)32 * N4K * 4;
  float* ps2 = (float*)w;  w += (size_t)32 * N4K * 4;
  float* uvec = (float*)w; w += N4K * 4;
  float* vvec = (float*)w; w += N4K * 4;
  float* ctE = (float*)w;  w += N4K * 4;
  float* dmax1 = (float*)w; w += 256;
  float* dmax2 = (float*)w; w += 256;

  const dim3 b256(256);

  k_normalize<<<1024, b256, 0, stream>>>(f1, X1);
  k_normalize<<<1024, b256, 0, stream>>>(f2, X2);
  k_transpose<<<dim3(4, 64), b256, 0, stream>>>(X1, X1t, N4K, DFEAT);
  k_transpose<<<dim3(4, 64), b256, 0, stream>>>(X2, X2t, N4K, DFEAT);

  // ---- Gram stats: m1 from G1; m2 + column stats from G2 ----
  k_gemm_bt<<<dim3(32, 32, 1), b256, 0, stream>>>(X1, X1, DFEAT, DFEAT, Sbuf, nullptr,
                                                  N4K, 1, nullptr, nullptr, nullptr);
  k_zero1<<<1, 64, 0, stream>>>(dmax1);
  k_stats<<<dim3(2, 32), b256, 0, stream>>>(Sbuf, ps1, ps2, dmax1);
  k_gemm_bt<<<dim3(32, 32, 1), b256, 0, stream>>>(X2, X2, DFEAT, DFEAT, Sbuf, nullptr,
                                                  N4K, 1, nullptr, nullptr, nullptr);
  k_zero1<<<1, 64, 0, stream>>>(dmax2);
  k_stats<<<dim3(2, 32), b256, 0, stream>>>(Sbuf, ps1, ps2, dmax2);
  k_ctfinal<<<16, b256, 0, stream>>>(ps1, ps2, dmax1, dmax2, ctE);

  // ---- T = outer(p,q) = 2^-24 (bf16 0x3380, exact) ----
  k_fill_bf16<<<8192, b256, 0, stream>>>(T0, 0x33803380u);

  unsigned short* Tc = T0;
  unsigned short* Ko = T1;
  for (int it = 0; it < 5; it++) {
    float* Yp = (float*)Sbuf;   // [8][4096][256] fp32 = 32 MB
    // Y = T @ X2 (K-split by 8) -> partials
    k_gemm_bt<<<dim3(2, 32, 8), b256, 0, stream>>>(Tc, X2t, N4K, 512, nullptr, Yp,
                                                   DFEAT, 3, nullptr, nullptr, nullptr);
    k_redY<<<dim3(64, 4), b256, 0, stream>>>(Yp, Yt);
    // PT = Y^T @ X1 (K-split by 16) -> partials
    k_gemm_bt<<<dim3(2, 2, 16), b256, 0, stream>>>(Yt, X1t, N4K, 256, nullptr, Pp,
                                                   DFEAT, 3, nullptr, nullptr, nullptr);
    k_redPT<<<256, b256, 0, stream>>>(Pp, PTb);
    // Z = X1 @ P
    k_gemm_bt<<<dim3(2, 32, 1), b256, 0, stream>>>(X1, PTb, DFEAT, DFEAT, Zb, nullptr,
                                                   DFEAT, 0, nullptr, nullptr, nullptr);
    // K = exp(sArg * Z @ X2^T - ctE_j)
    k_gemm_bt<<<dim3(32, 32, 1), b256, 0, stream>>>(Zb, X2, DFEAT, DFEAT, Ko, nullptr,
                                                    N4K, 2, ctE, dmax1, dmax2);
    // Sinkhorn: 20 x { u = p/(K v) ; v = q/(K^T u) }, v0 = 1
    float* sp = (float*)Sbuf;   // 512 x 4096 fp32 partials (8 MB)
    k_setones<<<16, b256, 0, stream>>>(vvec);
    for (int s = 0; s < 20; s++) {
      k_sink<<<512, b256, 0, stream>>>(Ko, vvec, uvec, sp);
      k_sinkfin<<<128, b256, 0, stream>>>(sp, vvec);
    }
    if (it < 4) {
      k_scaleT<<<8192, b256, 0, stream>>>(Ko, uvec, vvec);  // K -> T in place
      unsigned short* tmp = Tc; Tc = Ko; Ko = tmp;
    }
  }
  k_loss<<<1, b256, 0, stream>>>(Ko, uvec, vvec, out);
}